// Round 18
// baseline (164.880 us; speedup 1.0000x reference)
//
#include <hip/hip_runtime.h>

typedef __attribute__((ext_vector_type(8))) short short8;
typedef __attribute__((ext_vector_type(4))) float f32x4;
typedef __attribute__((ext_vector_type(4))) unsigned short us4;

#define LOG2E 1.4426950408889634f

__device__ __forceinline__ unsigned short f2bf(float f) {
  unsigned int u = __float_as_uint(f);
  u += 0x7FFFu + ((u >> 16) & 1u);   // RNE (finite values only)
  return (unsigned short)(u >> 16);
}
__device__ __forceinline__ float bf2f(unsigned short s) {
  return __uint_as_float(((unsigned int)s) << 16);
}

// ---------------- fused convert (blocks 4..3075) + mask compaction (blocks 0..3)
__global__ __launch_bounds__(256) void cvt_mask_all(
    const float* __restrict__ x, const float* __restrict__ wq, const float* __restrict__ wk,
    const float* __restrict__ wv, const float* __restrict__ wo, const float* __restrict__ w1,
    const float* __restrict__ w2, const int* __restrict__ mask,
    unsigned short* __restrict__ xb, unsigned short* __restrict__ wqkvb,
    unsigned short* __restrict__ wob, unsigned short* __restrict__ w1b,
    unsigned short* __restrict__ w2b, int* __restrict__ srcp, int* __restrict__ cnt) {
  int tid = threadIdx.x;
  if (blockIdx.x < 4) {
    int b = blockIdx.x;
    const int4 mv = ((const int4*)(mask + b * 1024))[tid];
    int vals[4] = {mv.x != 0, mv.y != 0, mv.z != 0, mv.w != 0};
    int s4 = vals[0] + vals[1] + vals[2] + vals[3];
    __shared__ int sv[256];
    sv[tid] = s4;
    __syncthreads();
    for (int off = 1; off < 256; off <<= 1) {
      int t = (tid >= off) ? sv[tid - off] : 0;
      __syncthreads();
      sv[tid] += t;
      __syncthreads();
    }
    int excl = sv[tid] - s4;
    int total = sv[255];
    int r = excl;
#pragma unroll
    for (int i = 0; i < 4; ++i) {
      int s = tid * 4 + i;
      int d;
      if (vals[i]) { d = r; r++; }
      else         { d = total + s - r; }
      srcp[b * 1024 + d] = s;
    }
    if (tid == 0) cnt[b] = total;
    return;
  }
  int i = (blockIdx.x - 4) * 256 + tid;
  for (int t = i; t < 3145728; t += 786432) {
    const float* src; unsigned short* dst; int lo;
    if (t < 1048576)      { src = x;  dst = xb;              lo = t; }
    else if (t < 1310720) { src = wq; dst = wqkvb;           lo = t - 1048576; }
    else if (t < 1572864) { src = wk; dst = wqkvb + 1048576; lo = t - 1310720; }
    else if (t < 1835008) { src = wv; dst = wqkvb + 2097152; lo = t - 1572864; }
    else if (t < 2097152) { src = wo; dst = wob;             lo = t - 1835008; }
    else if (t < 2621440) { src = w1; dst = w1b;             lo = t - 2097152; }
    else                  { src = w2; dst = w2b;             lo = t - 2621440; }
    float4 v = ((const float4*)src)[lo];
    us4 o = { f2bf(v.x), f2bf(v.y), f2bf(v.z), f2bf(v.w) };
    *(us4*)(dst + (size_t)lo * 4) = o;
  }
}

#define GLL16(g, l) __builtin_amdgcn_global_load_lds( \
    (const __attribute__((address_space(1))) void*)(g), \
    (__attribute__((address_space(3))) void*)(l), 16, 0, 0)

// ---------------- gemm2: BM=128, BN in {64,128}, dbuf (R5-proven) -----------
// EPI 3: relu -> bf16 [M,N]
// EPI 5: bf16 out = acc + bias + res_bf16[m,n]
template <int BN, int EPI>
__global__ __launch_bounds__(256) void gemm2(
    const unsigned short* __restrict__ A, const unsigned short* __restrict__ B,
    const float* __restrict__ bias, const void* __restrict__ res,
    void* __restrict__ out, int M, int N, int K) {
  __shared__ __align__(16) unsigned short As[2][128 * 64];
  __shared__ __align__(16) unsigned short Bs[2][BN * 64];
  const int tid = threadIdx.x;
  const int lane = tid & 63;
  const int w = tid >> 6;
  const int l15 = lane & 15, l4 = lane >> 4;
  const int m0 = blockIdx.y * 128, n0 = blockIdx.x * BN;

  constexpr int MI = (BN == 128) ? 4 : 2;
  f32x4 acc[MI][4] = {};

  auto STAGE = [&](int buf, int kt) {
#pragma unroll
    for (int i = 0; i < 4; ++i) {
      int chunk = i * 4 + w;
      int c = chunk * 64 + lane;
      int row = c >> 3;
      int srcb = ((c & 7) * 16) ^ ((row & 7) << 4);
      GLL16(A + (size_t)(m0 + row) * K + kt * 64 + (srcb >> 1), &As[buf][chunk * 512]);
    }
#pragma unroll
    for (int i = 0; i < BN / 32; ++i) {
      int chunk = i * 4 + w;
      int c = chunk * 64 + lane;
      int row = c >> 3;
      int srcb = ((c & 7) * 16) ^ ((row & 7) << 4);
      GLL16(B + (size_t)(n0 + row) * K + kt * 64 + (srcb >> 1), &Bs[buf][chunk * 512]);
    }
  };

  const int nkt = K >> 6;
  STAGE(0, 0);
  __syncthreads();
  int cur = 0;
  for (int kt = 0; kt < nkt; ++kt) {
    if (kt + 1 < nkt) STAGE(cur ^ 1, kt + 1);
    const unsigned short* as = As[cur];
    const unsigned short* bs = Bs[cur];
#pragma unroll
    for (int ks = 0; ks < 2; ++ks) {
      short8 a[MI], b[4];
#pragma unroll
      for (int mi = 0; mi < MI; ++mi) {
        int row = (BN == 128 ? ((w >> 1) * 64) : (w * 32)) + mi * 16 + l15;
        int ke = (ks * 32 + l4 * 8) ^ ((row & 7) << 3);
        a[mi] = *(const short8*)(as + row * 64 + ke);
      }
#pragma unroll
      for (int ni = 0; ni < 4; ++ni) {
        int row = (BN == 128 ? ((w & 1) * 64) : 0) + ni * 16 + l15;
        int ke = (ks * 32 + l4 * 8) ^ ((row & 7) << 3);
        b[ni] = *(const short8*)(bs + row * 64 + ke);
      }
#pragma unroll
      for (int mi = 0; mi < MI; ++mi)
#pragma unroll
        for (int ni = 0; ni < 4; ++ni)
          acc[mi][ni] = __builtin_amdgcn_mfma_f32_16x16x32_bf16(a[mi], b[ni], acc[mi][ni], 0, 0, 0);
    }
    __syncthreads();
    cur ^= 1;
  }

#pragma unroll
  for (int mi = 0; mi < MI; ++mi) {
#pragma unroll
    for (int ni = 0; ni < 4; ++ni) {
      int n = n0 + (BN == 128 ? ((w & 1) * 64) : 0) + ni * 16 + l15;
      float bv = bias[n];
#pragma unroll
      for (int j = 0; j < 4; ++j) {
        int m = m0 + (BN == 128 ? ((w >> 1) * 64) : (w * 32)) + mi * 16 + l4 * 4 + j;
        float v = acc[mi][ni][j] + bv;
        size_t idx = (size_t)m * N + n;
        if (EPI == 3) {
          ((unsigned short*)out)[idx] = f2bf(v > 0.f ? v : 0.f);
        } else {
          ((unsigned short*)out)[idx] = f2bf(v + bf2f(((const unsigned short*)res)[idx]));
        }
      }
    }
  }
}

// ---------------- fused QKV GEMM (dbuf, BM=128, BN=64, gather + dead-tail skip)
__global__ __launch_bounds__(256) void gemm_qkv(
    const unsigned short* __restrict__ A,   // [4096,1024]
    const unsigned short* __restrict__ Bw,  // [3072,1024]
    const float* __restrict__ bq, const float* __restrict__ bk, const float* __restrict__ bvv,
    const int* __restrict__ srcp, const int* __restrict__ cntg,
    unsigned short* __restrict__ Qo, unsigned short* __restrict__ Ko, unsigned short* __restrict__ Vto,
    int K) {
  __shared__ __align__(16) unsigned short As[2][128 * 64];
  __shared__ __align__(16) unsigned short Bs[2][64 * 64];
  const int tid = threadIdx.x;
  const int lane = tid & 63;
  const int w = tid >> 6;
  const int l15 = lane & 15, l4 = lane >> 4;
  const int m0 = blockIdx.y * 128, n0 = blockIdx.x * 64;
  const bool swp = (n0 >= 2048);   // V segment
  const bool gat = (n0 >= 1024);   // K and V segments gather A rows

  // dead-tail skip: compacted positions >= cnt are never read by attention
  if (gat && (m0 & 1023) >= cntg[m0 >> 10]) return;

  int arow[4];
#pragma unroll
  for (int i = 0; i < 4; ++i) {
    int chunk = i * 4 + w;
    int m = m0 + ((chunk * 64 + lane) >> 3);
    arow[i] = gat ? ((m & ~1023) + srcp[m]) : m;
  }

  f32x4 acc[2][4] = {};

  auto STAGE = [&](int buf, int kt) {
#pragma unroll
    for (int i = 0; i < 4; ++i) {
      int chunk = i * 4 + w;
      int c = chunk * 64 + lane;
      int srcb = ((c & 7) * 16) ^ (((c >> 3) & 7) << 4);
      GLL16(A + (size_t)arow[i] * K + kt * 64 + (srcb >> 1), &As[buf][chunk * 512]);
    }
#pragma unroll
    for (int i = 0; i < 2; ++i) {
      int chunk = i * 4 + w;
      int c = chunk * 64 + lane;
      int row = c >> 3;
      int srcb = ((c & 7) * 16) ^ ((row & 7) << 4);
      GLL16(Bw + (size_t)(n0 + row) * K + kt * 64 + (srcb >> 1), &Bs[buf][chunk * 512]);
    }
  };

  const int nkt = K >> 6;
  STAGE(0, 0);
  __syncthreads();
  int cur = 0;
  for (int kt = 0; kt < nkt; ++kt) {
    if (kt + 1 < nkt) STAGE(cur ^ 1, kt + 1);
    const unsigned short* as = As[cur];
    const unsigned short* bs = Bs[cur];
#pragma unroll
    for (int ks = 0; ks < 2; ++ks) {
      short8 a[2], b[4];
#pragma unroll
      for (int mi = 0; mi < 2; ++mi) {
        int row = w * 32 + mi * 16 + l15;
        int ke = (ks * 32 + l4 * 8) ^ ((row & 7) << 3);
        a[mi] = *(const short8*)(as + row * 64 + ke);
      }
#pragma unroll
      for (int ni = 0; ni < 4; ++ni) {
        int row = ni * 16 + l15;
        int ke = (ks * 32 + l4 * 8) ^ ((row & 7) << 3);
        b[ni] = *(const short8*)(bs + row * 64 + ke);
      }
      if (!swp) {
#pragma unroll
        for (int mi = 0; mi < 2; ++mi)
#pragma unroll
          for (int ni = 0; ni < 4; ++ni)
            acc[mi][ni] = __builtin_amdgcn_mfma_f32_16x16x32_bf16(a[mi], b[ni], acc[mi][ni], 0, 0, 0);
      } else {
#pragma unroll
        for (int mi = 0; mi < 2; ++mi)
#pragma unroll
          for (int ni = 0; ni < 4; ++ni)
            acc[mi][ni] = __builtin_amdgcn_mfma_f32_16x16x32_bf16(b[ni], a[mi], acc[mi][ni], 0, 0, 0);
      }
    }
    __syncthreads();
    cur ^= 1;
  }

  if (!swp) {
#pragma unroll
    for (int mi = 0; mi < 2; ++mi) {
#pragma unroll
      for (int ni = 0; ni < 4; ++ni) {
        int n = n0 + ni * 16 + l15;
        int seg = n >> 10;
        int nn = n & 1023;
        int h_ = nn >> 6, d_ = nn & 63;
        float bval = (seg == 0 ? bq : bk)[nn];
#pragma unroll
        for (int j = 0; j < 4; ++j) {
          int m = m0 + w * 32 + mi * 16 + l4 * 4 + j;
          int b_ = m >> 10, s_ = m & 1023;
          float v = acc[mi][ni][j] + bval;
          size_t headbase = ((size_t)(b_ * 16 + h_)) << 16;
          if (seg == 0) Qo[headbase + (s_ << 6) + d_] = f2bf(v * 0.125f);
          else          Ko[headbase + (s_ << 6) + d_] = f2bf(v);
        }
      }
    }
  } else {
#pragma unroll
    for (int ni = 0; ni < 4; ++ni) {
      float bval[4];
      int nbase = (n0 & 1023) + ni * 16 + l4 * 4;
#pragma unroll
      for (int j = 0; j < 4; ++j) bval[j] = bvv[nbase + j];
#pragma unroll
      for (int mi = 0; mi < 2; ++mi) {
        int m = m0 + w * 32 + mi * 16 + l15;
        int b_ = m >> 10, s_ = m & 1023;
#pragma unroll
        for (int j = 0; j < 4; ++j) {
          int nn = nbase + j;
          int h_ = nn >> 6, d_ = nn & 63;
          float v = acc[mi][ni][j] + bval[j];
          Vto[(((size_t)(b_ * 16 + h_)) << 16) + (d_ << 10) + s_] = f2bf(v);
        }
      }
    }
  }
}

// ---------------- flash attention over COMPACTED keys (+ T5 setprio) --------
__global__ __launch_bounds__(256) void attn_kernel(
    const unsigned short* __restrict__ Qg, const unsigned short* __restrict__ Kg,
    const unsigned short* __restrict__ Vtg, const int* __restrict__ cntg,
    unsigned short* __restrict__ Og) {
  __shared__ __align__(16) unsigned short Qs[64 * 64];
  __shared__ __align__(16) unsigned short Ks[64 * 64];
  __shared__ __align__(16) unsigned short Vs[64 * 64];
  __shared__ __align__(16) unsigned short Ps[4][16 * 64];

  const int tid = threadIdx.x, lane = tid & 63, w = tid >> 6;
  const int l15 = lane & 15, l4 = lane >> 4;
  const int bh = blockIdx.x;                 // bh on x: same-bh blocks share XCD
  const int b = bh >> 4, h = bh & 15;
  const int s0 = blockIdx.y * 64;

  const unsigned short* Qbase = Qg + ((size_t)bh << 16);
  const unsigned short* Kbase = Kg + ((size_t)bh << 16);
  const unsigned short* Vbase = Vtg + ((size_t)bh << 16);

  const int cnt = cntg[b];
  const int nkt = (cnt + 63) >> 6;

#pragma unroll
  for (int i = 0; i < 2; ++i) {
    int c = i * 256 + tid;
    int row = c >> 3, off8 = (c & 7) * 8;
    short8 v = *(const short8*)(Qbase + (size_t)(s0 + row) * 64 + off8);
    *(short8*)(&Qs[row * 64 + (off8 ^ ((row & 7) << 3))]) = v;
  }

  const int c0 = tid, c1 = 256 + tid;
  const int r0 = c0 >> 3, o0 = (c0 & 7) * 8;
  const int r1 = c1 >> 3, o1 = (c1 & 7) * 8;   // o1 == o0 (256 % 8 == 0)
  const int li0 = r0 * 64 + (o0 ^ ((r0 & 7) << 3));
  const int li1 = r1 * 64 + (o1 ^ ((r1 & 7) << 3));

  short8 kA, kB, vA, vB;
#define LOADKV(kv0) do { \
    kA = *(const short8*)(Kbase + (size_t)((kv0) + r0) * 64 + o0); \
    kB = *(const short8*)(Kbase + (size_t)((kv0) + r1) * 64 + o1); \
    vA = *(const short8*)(Vbase + (size_t)r0 * 1024 + (kv0) + o0); \
    vB = *(const short8*)(Vbase + (size_t)r1 * 1024 + (kv0) + o1); \
  } while (0)

  f32x4 o[4] = {};
  float l_st[4] = {0.f, 0.f, 0.f, 0.f};

  LOADKV(0);
  for (int kv = 0; kv < nkt; ++kv) {
    int kv0 = kv * 64;
    __syncthreads();
    if (kv0 + 64 > cnt) {
      // tail tile: zero V elements at invalid k (stale memory may be inf/NaN)
      int k0 = kv0 + o0;
#pragma unroll
      for (int e = 0; e < 8; ++e)
        if (k0 + e >= cnt) { vA[e] = 0; vB[e] = 0; }
    }
    *(short8*)(&Ks[li0]) = kA;
    *(short8*)(&Ks[li1]) = kB;
    *(short8*)(&Vs[li0]) = vA;
    *(short8*)(&Vs[li1]) = vB;
    __syncthreads();
    if (kv + 1 < nkt) LOADKV(kv0 + 64);

    f32x4 sc[4] = {};
    __builtin_amdgcn_s_setprio(1);
#pragma unroll
    for (int ks = 0; ks < 2; ++ks) {
      short8 a, bb[4];
      {
        int row = w * 16 + l15;
        int ke = (ks * 32 + l4 * 8) ^ ((row & 7) << 3);
        a = *(const short8*)(Qs + row * 64 + ke);
      }
#pragma unroll
      for (int ni = 0; ni < 4; ++ni) {
        int row = ni * 16 + l15;
        int ke = (ks * 32 + l4 * 8) ^ ((row & 7) << 3);
        bb[ni] = *(const short8*)(Ks + row * 64 + ke);
      }
#pragma unroll
      for (int ni = 0; ni < 4; ++ni)
        sc[ni] = __builtin_amdgcn_mfma_f32_16x16x32_bf16(a, bb[ni], sc[ni], 0, 0, 0);
    }
    __builtin_amdgcn_s_setprio(0);

    if (kv0 + 64 <= cnt) {
#pragma unroll
      for (int j = 0; j < 4; ++j) {
        int r = l4 * 4 + j;
        float ps = 0.f;
#pragma unroll
        for (int ni = 0; ni < 4; ++ni) {
          int cc = ni * 16 + l15;
          float p = exp2f(sc[ni][j] * LOG2E);
          ps += p;
          Ps[w][r * 64 + (cc ^ ((r & 7) << 3))] = f2bf(p);
        }
        l_st[j] += ps;
      }
    } else {
      bool val[4];
#pragma unroll
      for (int ni = 0; ni < 4; ++ni) val[ni] = (kv0 + ni * 16 + l15) < cnt;
#pragma unroll
      for (int j = 0; j < 4; ++j) {
        int r = l4 * 4 + j;
        float ps = 0.f;
#pragma unroll
        for (int ni = 0; ni < 4; ++ni) {
          int cc = ni * 16 + l15;
          float p = exp2f(sc[ni][j] * LOG2E);
          p = val[ni] ? p : 0.f;   // select BEFORE use: kills inf/NaN from stale K
          ps += p;
          Ps[w][r * 64 + (cc ^ ((r & 7) << 3))] = f2bf(p);
        }
        l_st[j] += ps;
      }
    }

    __builtin_amdgcn_s_setprio(1);
#pragma unroll
    for (int ks = 0; ks < 2; ++ks) {
      short8 a, bb[4];
      {
        int row = l15;
        int ke = (ks * 32 + l4 * 8) ^ ((row & 7) << 3);
        a = *(const short8*)(&Ps[w][row * 64 + ke]);
      }
#pragma unroll
      for (int dt = 0; dt < 4; ++dt) {
        int row = dt * 16 + l15;
        int ke = (ks * 32 + l4 * 8) ^ ((row & 7) << 3);
        bb[dt] = *(const short8*)(Vs + row * 64 + ke);
      }
#pragma unroll
      for (int dt = 0; dt < 4; ++dt)
        o[dt] = __builtin_amdgcn_mfma_f32_16x16x32_bf16(a, bb[dt], o[dt], 0, 0, 0);
    }
    __builtin_amdgcn_s_setprio(0);
  }
#undef LOADKV

#pragma unroll
  for (int j = 0; j < 4; ++j) {
#pragma unroll
    for (int off = 1; off < 16; off <<= 1) l_st[j] += __shfl_xor(l_st[j], off, 64);
  }

#pragma unroll
  for (int j = 0; j < 4; ++j) {
    float inv = 1.f / l_st[j];
    int s = s0 + w * 16 + l4 * 4 + j;
#pragma unroll
    for (int dt = 0; dt < 4; ++dt) {
      int d = dt * 16 + l15;
      Og[(((size_t)(b * 1024 + s)) << 10) + h * 64 + d] = f2bf(o[dt][j] * inv);
    }
  }
}

// ---------------- LayerNorm over bf16 z (unbiased std, /(std+eps)) ----------
template <int OUTF32>
__global__ __launch_bounds__(256) void ln_kernel(
    const unsigned short* __restrict__ z, const float* __restrict__ g,
    const float* __restrict__ be, float* __restrict__ outf,
    unsigned short* __restrict__ outb) {
  int row = blockIdx.x * 4 + (threadIdx.x >> 6);
  int lane = threadIdx.x & 63;
  const short8* zp = (const short8*)(z + (size_t)row * 1024);
  float f[16];
  float sum = 0.f, sq = 0.f;
#pragma unroll
  for (int half = 0; half < 2; ++half) {
    short8 v = zp[lane + half * 64];
#pragma unroll
    for (int k = 0; k < 8; ++k) {
      float x = bf2f((unsigned short)v[k]);
      f[half * 8 + k] = x;
      sum += x;
      sq += x * x;
    }
  }
#pragma unroll
  for (int off = 1; off < 64; off <<= 1) {
    sum += __shfl_xor(sum, off, 64);
    sq += __shfl_xor(sq, off, 64);
  }
  float mean = sum * (1.f / 1024.f);
  float var = fmaxf((sq - sum * mean) * (1.f / 1023.f), 0.f);
  float r = 1.f / (sqrtf(var) + 1e-6f);
#pragma unroll
  for (int half = 0; half < 2; ++half) {
    int c0 = half * 512 + lane * 8;
    float4 g0 = *(const float4*)(g + c0);
    float4 g1 = *(const float4*)(g + c0 + 4);
    float4 b0 = *(const float4*)(be + c0);
    float4 b1 = *(const float4*)(be + c0 + 4);
    float y[8];
    y[0] = (f[half * 8 + 0] - mean) * r * g0.x + b0.x;
    y[1] = (f[half * 8 + 1] - mean) * r * g0.y + b0.y;
    y[2] = (f[half * 8 + 2] - mean) * r * g0.z + b0.z;
    y[3] = (f[half * 8 + 3] - mean) * r * g0.w + b0.w;
    y[4] = (f[half * 8 + 4] - mean) * r * g1.x + b1.x;
    y[5] = (f[half * 8 + 5] - mean) * r * g1.y + b1.y;
    y[6] = (f[half * 8 + 6] - mean) * r * g1.z + b1.z;
    y[7] = (f[half * 8 + 7] - mean) * r * g1.w + b1.w;
    if (OUTF32) {
      float4 o0 = {y[0], y[1], y[2], y[3]};
      float4 o1 = {y[4], y[5], y[6], y[7]};
      *(float4*)(outf + (size_t)row * 1024 + c0) = o0;
      *(float4*)(outf + (size_t)row * 1024 + c0 + 4) = o1;
    } else {
      us4 o0 = {f2bf(y[0]), f2bf(y[1]), f2bf(y[2]), f2bf(y[3])};
      us4 o1 = {f2bf(y[4]), f2bf(y[5]), f2bf(y[6]), f2bf(y[7])};
      *(us4*)(outb + (size_t)row * 1024 + c0) = o0;
      *(us4*)(outb + (size_t)row * 1024 + c0 + 4) = o1;
    }
  }
}

extern "C" void kernel_launch(void* const* d_in, const int* in_sizes, int n_in,
                              void* d_out, int out_size, void* d_ws, size_t ws_size,
                              hipStream_t stream) {
  (void)in_sizes; (void)n_in; (void)out_size; (void)ws_size;
  const float* x   = (const float*)d_in[0];
  const int*   msk = (const int*)d_in[1];
  const float* wq  = (const float*)d_in[2];
  const float* bq  = (const float*)d_in[3];
  const float* wk  = (const float*)d_in[4];
  const float* bk  = (const float*)d_in[5];
  const float* wv  = (const float*)d_in[6];
  const float* bv  = (const float*)d_in[7];
  const float* wo  = (const float*)d_in[8];
  const float* bo  = (const float*)d_in[9];
  const float* w1  = (const float*)d_in[10];
  const float* b1  = (const float*)d_in[11];
  const float* w2  = (const float*)d_in[12];
  const float* b2  = (const float*)d_in[13];
  const float* g1  = (const float*)d_in[14];
  const float* be1 = (const float*)d_in[15];
  const float* g2  = (const float*)d_in[16];
  const float* be2 = (const float*)d_in[17];
  float* out = (float*)d_out;

  char* ws = (char*)d_ws;
  const size_t MB = 1 << 20;
  unsigned short* xb    = (unsigned short*)(ws + 0 * MB);    // 8 MB
  unsigned short* wqkvb = (unsigned short*)(ws + 8 * MB);    // 6 MB [3072,1024] bf16
  unsigned short* wob   = (unsigned short*)(ws + 14 * MB);   // 2 MB
  unsigned short* w1b   = (unsigned short*)(ws + 16 * MB);   // 4 MB
  unsigned short* w2b   = (unsigned short*)(ws + 20 * MB);   // 4 MB
  unsigned short* Qb    = (unsigned short*)(ws + 24 * MB);   // 8 MB
  unsigned short* Kb    = (unsigned short*)(ws + 32 * MB);   // 8 MB
  unsigned short* Vtb   = (unsigned short*)(ws + 40 * MB);   // 8 MB
  unsigned short* attnb = (unsigned short*)(ws + 48 * MB);   // 8 MB
  unsigned short* z1b   = (unsigned short*)(ws + 56 * MB);   // 8 MB bf16
  unsigned short* x1b   = (unsigned short*)(ws + 64 * MB);   // 8 MB bf16
  unsigned short* z2b   = (unsigned short*)(ws + 72 * MB);   // 8 MB bf16
  unsigned short* h1    = (unsigned short*)(ws + 24 * MB);   // 16 MB, aliases Q/K (dead)
  int* srcp = (int*)(ws + 80 * MB);                          // 16 KB
  int* cnt  = srcp + 4096;                                   // 16 B

  dim3 blk(256);

  cvt_mask_all<<<3076, blk, 0, stream>>>(x, wq, wk, wv, wo, w1, w2, msk,
                                         xb, wqkvb, wob, w1b, w2b, srcp, cnt);

  gemm_qkv<<<dim3(48, 32), blk, 0, stream>>>(xb, wqkvb, bq, bk, bv, srcp, cnt, Qb, Kb, Vtb, 1024);

  attn_kernel<<<dim3(64, 16), blk, 0, stream>>>(Qb, Kb, Vtb, cnt, attnb);

  gemm2<64, 5><<<dim3(16, 32), blk, 0, stream>>>(attnb, wob, bo, (const void*)xb, (void*)z1b, 4096, 1024, 1024);
  ln_kernel<0><<<1024, blk, 0, stream>>>(z1b, g1, be1, nullptr, x1b);

  gemm2<128, 3><<<dim3(16, 32), blk, 0, stream>>>(x1b, w1b, b1, nullptr, (void*)h1, 4096, 2048, 1024);
  gemm2<64, 5><<<dim3(16, 32), blk, 0, stream>>>(h1, w2b, b2, (const void*)x1b, (void*)z2b, 4096, 1024, 2048);
  ln_kernel<1><<<1024, blk, 0, stream>>>(z2b, g2, be2, out, nullptr);
}

// Round 19
// 163.930 us; speedup vs baseline: 1.0058x; 1.0058x over previous
//
#include <hip/hip_runtime.h>

typedef __attribute__((ext_vector_type(8))) short short8;
typedef __attribute__((ext_vector_type(4))) float f32x4;
typedef __attribute__((ext_vector_type(4))) unsigned short us4;

#define LOG2E 1.4426950408889634f

__device__ __forceinline__ unsigned short f2bf(float f) {
  unsigned int u = __float_as_uint(f);
  u += 0x7FFFu + ((u >> 16) & 1u);   // RNE (finite values only)
  return (unsigned short)(u >> 16);
}
__device__ __forceinline__ float bf2f(unsigned short s) {
  return __uint_as_float(((unsigned int)s) << 16);
}

// ---------------- fused convert (blocks 4..3075) + mask compaction (blocks 0..3)
__global__ __launch_bounds__(256) void cvt_mask_all(
    const float* __restrict__ x, const float* __restrict__ wq, const float* __restrict__ wk,
    const float* __restrict__ wv, const float* __restrict__ wo, const float* __restrict__ w1,
    const float* __restrict__ w2, const int* __restrict__ mask,
    unsigned short* __restrict__ xb, unsigned short* __restrict__ wqkvb,
    unsigned short* __restrict__ wob, unsigned short* __restrict__ w1b,
    unsigned short* __restrict__ w2b, int* __restrict__ srcp, int* __restrict__ cnt) {
  int tid = threadIdx.x;
  if (blockIdx.x < 4) {
    int b = blockIdx.x;
    const int4 mv = ((const int4*)(mask + b * 1024))[tid];
    int vals[4] = {mv.x != 0, mv.y != 0, mv.z != 0, mv.w != 0};
    int s4 = vals[0] + vals[1] + vals[2] + vals[3];
    __shared__ int sv[256];
    sv[tid] = s4;
    __syncthreads();
    for (int off = 1; off < 256; off <<= 1) {
      int t = (tid >= off) ? sv[tid - off] : 0;
      __syncthreads();
      sv[tid] += t;
      __syncthreads();
    }
    int excl = sv[tid] - s4;
    int total = sv[255];
    int r = excl;
#pragma unroll
    for (int i = 0; i < 4; ++i) {
      int s = tid * 4 + i;
      int d;
      if (vals[i]) { d = r; r++; }
      else         { d = total + s - r; }
      srcp[b * 1024 + d] = s;
    }
    if (tid == 0) cnt[b] = total;
    return;
  }
  int i = (blockIdx.x - 4) * 256 + tid;
  for (int t = i; t < 3145728; t += 786432) {
    const float* src; unsigned short* dst; int lo;
    if (t < 1048576)      { src = x;  dst = xb;              lo = t; }
    else if (t < 1310720) { src = wq; dst = wqkvb;           lo = t - 1048576; }
    else if (t < 1572864) { src = wk; dst = wqkvb + 1048576; lo = t - 1310720; }
    else if (t < 1835008) { src = wv; dst = wqkvb + 2097152; lo = t - 1572864; }
    else if (t < 2097152) { src = wo; dst = wob;             lo = t - 1835008; }
    else if (t < 2621440) { src = w1; dst = w1b;             lo = t - 2097152; }
    else                  { src = w2; dst = w2b;             lo = t - 2621440; }
    float4 v = ((const float4*)src)[lo];
    us4 o = { f2bf(v.x), f2bf(v.y), f2bf(v.z), f2bf(v.w) };
    *(us4*)(dst + (size_t)lo * 4) = o;
  }
}

#define GLL16(g, l) __builtin_amdgcn_global_load_lds( \
    (const __attribute__((address_space(1))) void*)(g), \
    (__attribute__((address_space(3))) void*)(l), 16, 0, 0)

// ---------------- gemm2: BM=128, BN in {64,128}, dbuf (R5-proven) -----------
// EPI 3: relu -> bf16 [M,N]
// EPI 5: bf16 out = acc + bias + res_bf16[m,n]
template <int BN, int EPI>
__global__ __launch_bounds__(256) void gemm2(
    const unsigned short* __restrict__ A, const unsigned short* __restrict__ B,
    const float* __restrict__ bias, const void* __restrict__ res,
    void* __restrict__ out, int M, int N, int K) {
  __shared__ __align__(16) unsigned short As[2][128 * 64];
  __shared__ __align__(16) unsigned short Bs[2][BN * 64];
  const int tid = threadIdx.x;
  const int lane = tid & 63;
  const int w = tid >> 6;
  const int l15 = lane & 15, l4 = lane >> 4;
  const int m0 = blockIdx.y * 128, n0 = blockIdx.x * BN;

  constexpr int MI = (BN == 128) ? 4 : 2;
  f32x4 acc[MI][4] = {};

  auto STAGE = [&](int buf, int kt) {
#pragma unroll
    for (int i = 0; i < 4; ++i) {
      int chunk = i * 4 + w;
      int c = chunk * 64 + lane;
      int row = c >> 3;
      int srcb = ((c & 7) * 16) ^ ((row & 7) << 4);
      GLL16(A + (size_t)(m0 + row) * K + kt * 64 + (srcb >> 1), &As[buf][chunk * 512]);
    }
#pragma unroll
    for (int i = 0; i < BN / 32; ++i) {
      int chunk = i * 4 + w;
      int c = chunk * 64 + lane;
      int row = c >> 3;
      int srcb = ((c & 7) * 16) ^ ((row & 7) << 4);
      GLL16(B + (size_t)(n0 + row) * K + kt * 64 + (srcb >> 1), &Bs[buf][chunk * 512]);
    }
  };

  const int nkt = K >> 6;
  STAGE(0, 0);
  __syncthreads();
  int cur = 0;
  for (int kt = 0; kt < nkt; ++kt) {
    if (kt + 1 < nkt) STAGE(cur ^ 1, kt + 1);
    const unsigned short* as = As[cur];
    const unsigned short* bs = Bs[cur];
#pragma unroll
    for (int ks = 0; ks < 2; ++ks) {
      short8 a[MI], b[4];
#pragma unroll
      for (int mi = 0; mi < MI; ++mi) {
        int row = (BN == 128 ? ((w >> 1) * 64) : (w * 32)) + mi * 16 + l15;
        int ke = (ks * 32 + l4 * 8) ^ ((row & 7) << 3);
        a[mi] = *(const short8*)(as + row * 64 + ke);
      }
#pragma unroll
      for (int ni = 0; ni < 4; ++ni) {
        int row = (BN == 128 ? ((w & 1) * 64) : 0) + ni * 16 + l15;
        int ke = (ks * 32 + l4 * 8) ^ ((row & 7) << 3);
        b[ni] = *(const short8*)(bs + row * 64 + ke);
      }
#pragma unroll
      for (int mi = 0; mi < MI; ++mi)
#pragma unroll
        for (int ni = 0; ni < 4; ++ni)
          acc[mi][ni] = __builtin_amdgcn_mfma_f32_16x16x32_bf16(a[mi], b[ni], acc[mi][ni], 0, 0, 0);
    }
    __syncthreads();
    cur ^= 1;
  }

#pragma unroll
  for (int mi = 0; mi < MI; ++mi) {
#pragma unroll
    for (int ni = 0; ni < 4; ++ni) {
      int n = n0 + (BN == 128 ? ((w & 1) * 64) : 0) + ni * 16 + l15;
      float bv = bias[n];
#pragma unroll
      for (int j = 0; j < 4; ++j) {
        int m = m0 + (BN == 128 ? ((w >> 1) * 64) : (w * 32)) + mi * 16 + l4 * 4 + j;
        float v = acc[mi][ni][j] + bv;
        size_t idx = (size_t)m * N + n;
        if (EPI == 3) {
          ((unsigned short*)out)[idx] = f2bf(v > 0.f ? v : 0.f);
        } else {
          ((unsigned short*)out)[idx] = f2bf(v + bf2f(((const unsigned short*)res)[idx]));
        }
      }
    }
  }
}

// ---------------- fused QKV GEMM (dbuf, BM=128, BN=64, gather + dead-tail skip)
__global__ __launch_bounds__(256) void gemm_qkv(
    const unsigned short* __restrict__ A,   // [4096,1024]
    const unsigned short* __restrict__ Bw,  // [3072,1024]
    const float* __restrict__ bq, const float* __restrict__ bk, const float* __restrict__ bvv,
    const int* __restrict__ srcp, const int* __restrict__ cntg,
    unsigned short* __restrict__ Qo, unsigned short* __restrict__ Ko, unsigned short* __restrict__ Vto,
    int K) {
  __shared__ __align__(16) unsigned short As[2][128 * 64];
  __shared__ __align__(16) unsigned short Bs[2][64 * 64];
  const int tid = threadIdx.x;
  const int lane = tid & 63;
  const int w = tid >> 6;
  const int l15 = lane & 15, l4 = lane >> 4;
  const int m0 = blockIdx.y * 128, n0 = blockIdx.x * 64;
  const bool swp = (n0 >= 2048);   // V segment
  const bool gat = (n0 >= 1024);   // K and V segments gather A rows

  // dead-tail skip: compacted positions >= cnt are never read by attention
  if (gat && (m0 & 1023) >= cntg[m0 >> 10]) return;

  int arow[4];
#pragma unroll
  for (int i = 0; i < 4; ++i) {
    int chunk = i * 4 + w;
    int m = m0 + ((chunk * 64 + lane) >> 3);
    arow[i] = gat ? ((m & ~1023) + srcp[m]) : m;
  }

  f32x4 acc[2][4] = {};

  auto STAGE = [&](int buf, int kt) {
#pragma unroll
    for (int i = 0; i < 4; ++i) {
      int chunk = i * 4 + w;
      int c = chunk * 64 + lane;
      int srcb = ((c & 7) * 16) ^ (((c >> 3) & 7) << 4);
      GLL16(A + (size_t)arow[i] * K + kt * 64 + (srcb >> 1), &As[buf][chunk * 512]);
    }
#pragma unroll
    for (int i = 0; i < 2; ++i) {
      int chunk = i * 4 + w;
      int c = chunk * 64 + lane;
      int row = c >> 3;
      int srcb = ((c & 7) * 16) ^ ((row & 7) << 4);
      GLL16(Bw + (size_t)(n0 + row) * K + kt * 64 + (srcb >> 1), &Bs[buf][chunk * 512]);
    }
  };

  const int nkt = K >> 6;
  STAGE(0, 0);
  __syncthreads();
  int cur = 0;
  for (int kt = 0; kt < nkt; ++kt) {
    if (kt + 1 < nkt) STAGE(cur ^ 1, kt + 1);
    const unsigned short* as = As[cur];
    const unsigned short* bs = Bs[cur];
#pragma unroll
    for (int ks = 0; ks < 2; ++ks) {
      short8 a[2], b[4];
#pragma unroll
      for (int mi = 0; mi < 2; ++mi) {
        int row = w * 32 + mi * 16 + l15;
        int ke = (ks * 32 + l4 * 8) ^ ((row & 7) << 3);
        a[mi] = *(const short8*)(as + row * 64 + ke);
      }
#pragma unroll
      for (int ni = 0; ni < 4; ++ni) {
        int row = ni * 16 + l15;
        int ke = (ks * 32 + l4 * 8) ^ ((row & 7) << 3);
        b[ni] = *(const short8*)(bs + row * 64 + ke);
      }
      if (!swp) {
#pragma unroll
        for (int mi = 0; mi < 2; ++mi)
#pragma unroll
          for (int ni = 0; ni < 4; ++ni)
            acc[mi][ni] = __builtin_amdgcn_mfma_f32_16x16x32_bf16(a[mi], b[ni], acc[mi][ni], 0, 0, 0);
      } else {
#pragma unroll
        for (int mi = 0; mi < 2; ++mi)
#pragma unroll
          for (int ni = 0; ni < 4; ++ni)
            acc[mi][ni] = __builtin_amdgcn_mfma_f32_16x16x32_bf16(b[ni], a[mi], acc[mi][ni], 0, 0, 0);
      }
    }
    __syncthreads();
    cur ^= 1;
  }

  if (!swp) {
#pragma unroll
    for (int mi = 0; mi < 2; ++mi) {
#pragma unroll
      for (int ni = 0; ni < 4; ++ni) {
        int n = n0 + ni * 16 + l15;
        int seg = n >> 10;
        int nn = n & 1023;
        int h_ = nn >> 6, d_ = nn & 63;
        float bval = (seg == 0 ? bq : bk)[nn];
#pragma unroll
        for (int j = 0; j < 4; ++j) {
          int m = m0 + w * 32 + mi * 16 + l4 * 4 + j;
          int b_ = m >> 10, s_ = m & 1023;
          float v = acc[mi][ni][j] + bval;
          size_t headbase = ((size_t)(b_ * 16 + h_)) << 16;
          if (seg == 0) Qo[headbase + (s_ << 6) + d_] = f2bf(v * 0.125f);
          else          Ko[headbase + (s_ << 6) + d_] = f2bf(v);
        }
      }
    }
  } else {
#pragma unroll
    for (int ni = 0; ni < 4; ++ni) {
      float bval[4];
      int nbase = (n0 & 1023) + ni * 16 + l4 * 4;
#pragma unroll
      for (int j = 0; j < 4; ++j) bval[j] = bvv[nbase + j];
#pragma unroll
      for (int mi = 0; mi < 2; ++mi) {
        int m = m0 + w * 32 + mi * 16 + l15;
        int b_ = m >> 10, s_ = m & 1023;
#pragma unroll
        for (int j = 0; j < 4; ++j) {
          int nn = nbase + j;
          int h_ = nn >> 6, d_ = nn & 63;
          float v = acc[mi][ni][j] + bval[j];
          Vto[(((size_t)(b_ * 16 + h_)) << 16) + (d_ << 10) + s_] = f2bf(v);
        }
      }
    }
  }
}

// ---------------- flash attention over COMPACTED keys ----------
__global__ __launch_bounds__(256) void attn_kernel(
    const unsigned short* __restrict__ Qg, const unsigned short* __restrict__ Kg,
    const unsigned short* __restrict__ Vtg, const int* __restrict__ cntg,
    unsigned short* __restrict__ Og) {
  __shared__ __align__(16) unsigned short Qs[64 * 64];
  __shared__ __align__(16) unsigned short Ks[64 * 64];
  __shared__ __align__(16) unsigned short Vs[64 * 64];
  __shared__ __align__(16) unsigned short Ps[4][16 * 64];

  const int tid = threadIdx.x, lane = tid & 63, w = tid >> 6;
  const int l15 = lane & 15, l4 = lane >> 4;
  const int bh = blockIdx.x;                 // bh on x: same-bh blocks share XCD
  const int b = bh >> 4, h = bh & 15;
  const int s0 = blockIdx.y * 64;

  const unsigned short* Qbase = Qg + ((size_t)bh << 16);
  const unsigned short* Kbase = Kg + ((size_t)bh << 16);
  const unsigned short* Vbase = Vtg + ((size_t)bh << 16);

  const int cnt = cntg[b];
  const int nkt = (cnt + 63) >> 6;

#pragma unroll
  for (int i = 0; i < 2; ++i) {
    int c = i * 256 + tid;
    int row = c >> 3, off8 = (c & 7) * 8;
    short8 v = *(const short8*)(Qbase + (size_t)(s0 + row) * 64 + off8);
    *(short8*)(&Qs[row * 64 + (off8 ^ ((row & 7) << 3))]) = v;
  }

  const int c0 = tid, c1 = 256 + tid;
  const int r0 = c0 >> 3, o0 = (c0 & 7) * 8;
  const int r1 = c1 >> 3, o1 = (c1 & 7) * 8;   // o1 == o0 (256 % 8 == 0)
  const int li0 = r0 * 64 + (o0 ^ ((r0 & 7) << 3));
  const int li1 = r1 * 64 + (o1 ^ ((r1 & 7) << 3));

  short8 kA, kB, vA, vB;
#define LOADKV(kv0) do { \
    kA = *(const short8*)(Kbase + (size_t)((kv0) + r0) * 64 + o0); \
    kB = *(const short8*)(Kbase + (size_t)((kv0) + r1) * 64 + o1); \
    vA = *(const short8*)(Vbase + (size_t)r0 * 1024 + (kv0) + o0); \
    vB = *(const short8*)(Vbase + (size_t)r1 * 1024 + (kv0) + o1); \
  } while (0)

  f32x4 o[4] = {};
  float l_st[4] = {0.f, 0.f, 0.f, 0.f};

  LOADKV(0);
  for (int kv = 0; kv < nkt; ++kv) {
    int kv0 = kv * 64;
    __syncthreads();
    if (kv0 + 64 > cnt) {
      // tail tile: zero V elements at invalid k (stale memory may be inf/NaN)
      int k0 = kv0 + o0;
#pragma unroll
      for (int e = 0; e < 8; ++e)
        if (k0 + e >= cnt) { vA[e] = 0; vB[e] = 0; }
    }
    *(short8*)(&Ks[li0]) = kA;
    *(short8*)(&Ks[li1]) = kB;
    *(short8*)(&Vs[li0]) = vA;
    *(short8*)(&Vs[li1]) = vB;
    __syncthreads();
    if (kv + 1 < nkt) LOADKV(kv0 + 64);

    f32x4 sc[4] = {};
#pragma unroll
    for (int ks = 0; ks < 2; ++ks) {
      short8 a, bb[4];
      {
        int row = w * 16 + l15;
        int ke = (ks * 32 + l4 * 8) ^ ((row & 7) << 3);
        a = *(const short8*)(Qs + row * 64 + ke);
      }
#pragma unroll
      for (int ni = 0; ni < 4; ++ni) {
        int row = ni * 16 + l15;
        int ke = (ks * 32 + l4 * 8) ^ ((row & 7) << 3);
        bb[ni] = *(const short8*)(Ks + row * 64 + ke);
      }
#pragma unroll
      for (int ni = 0; ni < 4; ++ni)
        sc[ni] = __builtin_amdgcn_mfma_f32_16x16x32_bf16(a, bb[ni], sc[ni], 0, 0, 0);
    }

    if (kv0 + 64 <= cnt) {
#pragma unroll
      for (int j = 0; j < 4; ++j) {
        int r = l4 * 4 + j;
        float ps = 0.f;
#pragma unroll
        for (int ni = 0; ni < 4; ++ni) {
          int cc = ni * 16 + l15;
          float p = exp2f(sc[ni][j] * LOG2E);
          ps += p;
          Ps[w][r * 64 + (cc ^ ((r & 7) << 3))] = f2bf(p);
        }
        l_st[j] += ps;
      }
    } else {
      bool val[4];
#pragma unroll
      for (int ni = 0; ni < 4; ++ni) val[ni] = (kv0 + ni * 16 + l15) < cnt;
#pragma unroll
      for (int j = 0; j < 4; ++j) {
        int r = l4 * 4 + j;
        float ps = 0.f;
#pragma unroll
        for (int ni = 0; ni < 4; ++ni) {
          int cc = ni * 16 + l15;
          float p = exp2f(sc[ni][j] * LOG2E);
          p = val[ni] ? p : 0.f;   // select BEFORE use: kills inf/NaN from stale K
          ps += p;
          Ps[w][r * 64 + (cc ^ ((r & 7) << 3))] = f2bf(p);
        }
        l_st[j] += ps;
      }
    }

#pragma unroll
    for (int ks = 0; ks < 2; ++ks) {
      short8 a, bb[4];
      {
        int row = l15;
        int ke = (ks * 32 + l4 * 8) ^ ((row & 7) << 3);
        a = *(const short8*)(&Ps[w][row * 64 + ke]);
      }
#pragma unroll
      for (int dt = 0; dt < 4; ++dt) {
        int row = dt * 16 + l15;
        int ke = (ks * 32 + l4 * 8) ^ ((row & 7) << 3);
        bb[dt] = *(const short8*)(Vs + row * 64 + ke);
      }
#pragma unroll
      for (int dt = 0; dt < 4; ++dt)
        o[dt] = __builtin_amdgcn_mfma_f32_16x16x32_bf16(a, bb[dt], o[dt], 0, 0, 0);
    }
  }
#undef LOADKV

#pragma unroll
  for (int j = 0; j < 4; ++j) {
#pragma unroll
    for (int off = 1; off < 16; off <<= 1) l_st[j] += __shfl_xor(l_st[j], off, 64);
  }

#pragma unroll
  for (int j = 0; j < 4; ++j) {
    float inv = 1.f / l_st[j];
    int s = s0 + w * 16 + l4 * 4 + j;
#pragma unroll
    for (int dt = 0; dt < 4; ++dt) {
      int d = dt * 16 + l15;
      Og[(((size_t)(b * 1024 + s)) << 10) + h * 64 + d] = f2bf(o[dt][j] * inv);
    }
  }
}

// ---------------- LayerNorm over bf16 z (unbiased std, /(std+eps)) ----------
template <int OUTF32>
__global__ __launch_bounds__(256) void ln_kernel(
    const unsigned short* __restrict__ z, const float* __restrict__ g,
    const float* __restrict__ be, float* __restrict__ outf,
    unsigned short* __restrict__ outb) {
  int row = blockIdx.x * 4 + (threadIdx.x >> 6);
  int lane = threadIdx.x & 63;
  const short8* zp = (const short8*)(z + (size_t)row * 1024);
  float f[16];
  float sum = 0.f, sq = 0.f;
#pragma unroll
  for (int half = 0; half < 2; ++half) {
    short8 v = zp[lane + half * 64];
#pragma unroll
    for (int k = 0; k < 8; ++k) {
      float x = bf2f((unsigned short)v[k]);
      f[half * 8 + k] = x;
      sum += x;
      sq += x * x;
    }
  }
#pragma unroll
  for (int off = 1; off < 64; off <<= 1) {
    sum += __shfl_xor(sum, off, 64);
    sq += __shfl_xor(sq, off, 64);
  }
  float mean = sum * (1.f / 1024.f);
  float var = fmaxf((sq - sum * mean) * (1.f / 1023.f), 0.f);
  float r = 1.f / (sqrtf(var) + 1e-6f);
#pragma unroll
  for (int half = 0; half < 2; ++half) {
    int c0 = half * 512 + lane * 8;
    float4 g0 = *(const float4*)(g + c0);
    float4 g1 = *(const float4*)(g + c0 + 4);
    float4 b0 = *(const float4*)(be + c0);
    float4 b1 = *(const float4*)(be + c0 + 4);
    float y[8];
    y[0] = (f[half * 8 + 0] - mean) * r * g0.x + b0.x;
    y[1] = (f[half * 8 + 1] - mean) * r * g0.y + b0.y;
    y[2] = (f[half * 8 + 2] - mean) * r * g0.z + b0.z;
    y[3] = (f[half * 8 + 3] - mean) * r * g0.w + b0.w;
    y[4] = (f[half * 8 + 4] - mean) * r * g1.x + b1.x;
    y[5] = (f[half * 8 + 5] - mean) * r * g1.y + b1.y;
    y[6] = (f[half * 8 + 6] - mean) * r * g1.z + b1.z;
    y[7] = (f[half * 8 + 7] - mean) * r * g1.w + b1.w;
    if (OUTF32) {
      float4 o0 = {y[0], y[1], y[2], y[3]};
      float4 o1 = {y[4], y[5], y[6], y[7]};
      *(float4*)(outf + (size_t)row * 1024 + c0) = o0;
      *(float4*)(outf + (size_t)row * 1024 + c0 + 4) = o1;
    } else {
      us4 o0 = {f2bf(y[0]), f2bf(y[1]), f2bf(y[2]), f2bf(y[3])};
      us4 o1 = {f2bf(y[4]), f2bf(y[5]), f2bf(y[6]), f2bf(y[7])};
      *(us4*)(outb + (size_t)row * 1024 + c0) = o0;
      *(us4*)(outb + (size_t)row * 1024 + c0 + 4) = o1;
    }
  }
}

extern "C" void kernel_launch(void* const* d_in, const int* in_sizes, int n_in,
                              void* d_out, int out_size, void* d_ws, size_t ws_size,
                              hipStream_t stream) {
  (void)in_sizes; (void)n_in; (void)out_size; (void)ws_size;
  const float* x   = (const float*)d_in[0];
  const int*   msk = (const int*)d_in[1];
  const float* wq  = (const float*)d_in[2];
  const float* bq  = (const float*)d_in[3];
  const float* wk  = (const float*)d_in[4];
  const float* bk  = (const float*)d_in[5];
  const float* wv  = (const float*)d_in[6];
  const float* bv  = (const float*)d_in[7];
  const float* wo  = (const float*)d_in[8];
  const float* bo  = (const float*)d_in[9];
  const float* w1  = (const float*)d_in[10];
  const float* b1  = (const float*)d_in[11];
  const float* w2  = (const float*)d_in[12];
  const float* b2  = (const float*)d_in[13];
  const float* g1  = (const float*)d_in[14];
  const float* be1 = (const float*)d_in[15];
  const float* g2  = (const float*)d_in[16];
  const float* be2 = (const float*)d_in[17];
  float* out = (float*)d_out;

  char* ws = (char*)d_ws;
  const size_t MB = 1 << 20;
  unsigned short* xb    = (unsigned short*)(ws + 0 * MB);    // 8 MB
  unsigned short* wqkvb = (unsigned short*)(ws + 8 * MB);    // 6 MB [3072,1024] bf16
  unsigned short* wob   = (unsigned short*)(ws + 14 * MB);   // 2 MB
  unsigned short* w1b   = (unsigned short*)(ws + 16 * MB);   // 4 MB
  unsigned short* w2b   = (unsigned short*)(ws + 20 * MB);   // 4 MB
  unsigned short* Qb    = (unsigned short*)(ws + 24 * MB);   // 8 MB
  unsigned short* Kb    = (unsigned short*)(ws + 32 * MB);   // 8 MB
  unsigned short* Vtb   = (unsigned short*)(ws + 40 * MB);   // 8 MB
  unsigned short* attnb = (unsigned short*)(ws + 48 * MB);   // 8 MB
  unsigned short* z1b   = (unsigned short*)(ws + 56 * MB);   // 8 MB bf16
  unsigned short* x1b   = (unsigned short*)(ws + 64 * MB);   // 8 MB bf16
  unsigned short* z2b   = (unsigned short*)(ws + 72 * MB);   // 8 MB bf16
  unsigned short* h1    = (unsigned short*)(ws + 24 * MB);   // 16 MB, aliases Q/K (dead)
  int* srcp = (int*)(ws + 80 * MB);                          // 16 KB
  int* cnt  = srcp + 4096;                                   // 16 B

  dim3 blk(256);

  cvt_mask_all<<<3076, blk, 0, stream>>>(x, wq, wk, wv, wo, w1, w2, msk,
                                         xb, wqkvb, wob, w1b, w2b, srcp, cnt);

  gemm_qkv<<<dim3(48, 32), blk, 0, stream>>>(xb, wqkvb, bq, bk, bv, srcp, cnt, Qb, Kb, Vtb, 1024);

  attn_kernel<<<dim3(64, 16), blk, 0, stream>>>(Qb, Kb, Vtb, cnt, attnb);

  gemm2<64, 5><<<dim3(16, 32), blk, 0, stream>>>(attnb, wob, bo, (const void*)xb, (void*)z1b, 4096, 1024, 1024);
  ln_kernel<0><<<1024, blk, 0, stream>>>(z1b, g1, be1, nullptr, x1b);

  gemm2<128, 3><<<dim3(16, 32), blk, 0, stream>>>(x1b, w1b, b1, nullptr, (void*)h1, 4096, 2048, 1024);
  gemm2<64, 5><<<dim3(16, 32), blk, 0, stream>>>(h1, w2b, b2, (const void*)x1b, (void*)z2b, 4096, 1024, 2048);
  ln_kernel<1><<<1024, blk, 0, stream>>>(z2b, g2, be2, out, nullptr);
}